// Round 1
// baseline (6078.149 us; speedup 1.0000x reference)
//
#include <hip/hip_runtime.h>
#include <hip/hip_bf16.h>

// GCN_27676769256197: 2-layer hetero GraphConv (TextGCN-like) on MI355X.
// Round 1: correctness-first fp32 implementation.
//   - degrees via f32 atomics (computed once, reused by both layers)
//   - per relation: h = X @ W (64x64-tile fp32 GEMM, row-scale rsqrt(deg_o)
//     folded into epilogue), then edge scatter-add with rsqrt(deg_i) folded
//     into the atomic add
//   - finalize: +bias, relu ; head: per-node dot(128) + sigmoid

#define N_W 50000
#define N_D 20000
#define E_WW 500000
#define E_WD 300000
#define DIM_IN 256
#define DIM_HID 128

// ---------------------------------------------------------------- degrees ---
__global__ __launch_bounds__(256) void degree_kernel(
    const int* __restrict__ src, const int* __restrict__ dst, int E,
    float* __restrict__ deg_o, float* __restrict__ deg_i) {
  int i = blockIdx.x * 256 + threadIdx.x;
  if (i < E) {
    atomicAdd(&deg_o[src[i]], 1.0f);
    atomicAdd(&deg_i[dst[i]], 1.0f);
  }
}

__global__ __launch_bounds__(256) void rsqrt_kernel(float* __restrict__ d, int n) {
  int i = blockIdx.x * 256 + threadIdx.x;
  if (i < n) d[i] = rsqrtf(fmaxf(d[i], 1.0f));
}

// ------------------------------------------------------------------- GEMM ---
// C[r][c] = S[r] * sum_k X[r][k] * W[k][c] ;  X:[M,K], W:[K,128], C:[M,128]
// block = 256 threads (16x16), tile 64 rows x 64 cols, 4x4 per thread.
template <int K>
__global__ __launch_bounds__(256) void gemm_kernel(
    const float* __restrict__ X, const float* __restrict__ S,
    const float* __restrict__ W, float* __restrict__ C, int M) {
  __shared__ float Xs[16][64];  // [kk][row]
  __shared__ float Ws[16][64];  // [kk][col]
  const int t = threadIdx.x;
  const int tx = t & 15;   // col group
  const int ty = t >> 4;   // row group
  const int row0 = blockIdx.x * 64;
  const int col0 = blockIdx.y * 64;

  float acc[4][4] = {{0.f}};

  for (int k0 = 0; k0 < K; k0 += 16) {
#pragma unroll
    for (int i = 0; i < 4; i++) {
      int j = t + i * 256;        // 0..1023
      int r = j >> 4, kk = j & 15;
      int gr = row0 + r;
      Xs[kk][r] = (gr < M) ? X[(long long)gr * K + (k0 + kk)] : 0.0f;
    }
#pragma unroll
    for (int i = 0; i < 4; i++) {
      int j = t + i * 256;
      int kk = j >> 6, c = j & 63;
      Ws[kk][c] = W[(long long)(k0 + kk) * 128 + col0 + c];
    }
    __syncthreads();
#pragma unroll
    for (int kk = 0; kk < 16; kk++) {
      float4 a = *(const float4*)&Xs[kk][ty * 4];
      float4 b = *(const float4*)&Ws[kk][tx * 4];
      acc[0][0] += a.x * b.x; acc[0][1] += a.x * b.y; acc[0][2] += a.x * b.z; acc[0][3] += a.x * b.w;
      acc[1][0] += a.y * b.x; acc[1][1] += a.y * b.y; acc[1][2] += a.y * b.z; acc[1][3] += a.y * b.w;
      acc[2][0] += a.z * b.x; acc[2][1] += a.z * b.y; acc[2][2] += a.z * b.z; acc[2][3] += a.z * b.w;
      acc[3][0] += a.w * b.x; acc[3][1] += a.w * b.y; acc[3][2] += a.w * b.z; acc[3][3] += a.w * b.w;
    }
    __syncthreads();
  }

#pragma unroll
  for (int i = 0; i < 4; i++) {
    int gr = row0 + ty * 4 + i;
    if (gr >= M) continue;
    float s = S[gr];
    float4 o = make_float4(acc[i][0] * s, acc[i][1] * s, acc[i][2] * s, acc[i][3] * s);
    *(float4*)&C[(long long)gr * 128 + col0 + tx * 4] = o;
  }
}

// ---------------------------------------------------------------- scatter ---
// acc[dst[e]][:] += h[src[e]][:] * rinv_i[dst[e]]   (128 feats, float4/thread)
__global__ __launch_bounds__(256) void scatter_kernel(
    const float* __restrict__ h, const int* __restrict__ src,
    const int* __restrict__ dst, const float* __restrict__ rinv,
    float* __restrict__ acc, int E) {
  long long i = (long long)blockIdx.x * 256 + threadIdx.x;
  long long total = (long long)E * 32;
  if (i >= total) return;
  int e = (int)(i >> 5);
  int f = ((int)i & 31) * 4;
  int s = src[e];
  int d = dst[e];
  float sc = rinv[d];
  float4 hv = *(const float4*)&h[(long long)s * 128 + f];
  float* ap = &acc[(long long)d * 128 + f];
  atomicAdd(ap + 0, hv.x * sc);
  atomicAdd(ap + 1, hv.y * sc);
  atomicAdd(ap + 2, hv.z * sc);
  atomicAdd(ap + 3, hv.w * sc);
}

// --------------------------------------------------------------- finalize ---
// acc[i] = relu(acc[i] + b0[f] (+ b1[f]) (+ b2[f]))
__global__ __launch_bounds__(256) void finalize_kernel(
    float* __restrict__ acc, const float* __restrict__ b0,
    const float* __restrict__ b1, const float* __restrict__ b2, long long n) {
  long long i = (long long)blockIdx.x * 256 + threadIdx.x;
  if (i >= n) return;
  int f = (int)(i & 127);
  float bb = b0[f];
  if (b1) bb += b1[f];
  if (b2) bb += b2[f];
  float v = acc[i] + bb;
  acc[i] = v > 0.0f ? v : 0.0f;
}

// ------------------------------------------------------------------- head ---
// out[n] = sigmoid(dot(X[n,:], w) + b) ; one wave per node, 4 nodes/block.
__global__ __launch_bounds__(256) void final_linear_kernel(
    const float* __restrict__ X, const float* __restrict__ w,
    const float* __restrict__ b, float* __restrict__ out, int n) {
  int wave = threadIdx.x >> 6;
  int lane = threadIdx.x & 63;
  int node = blockIdx.x * 4 + wave;
  if (node >= n) return;
  const float* xr = X + (long long)node * 128;
  float v = xr[lane] * w[lane] + xr[lane + 64] * w[lane + 64];
#pragma unroll
  for (int off = 32; off > 0; off >>= 1) v += __shfl_down(v, off);
  if (lane == 0) {
    float z = v + b[0];
    out[node] = 1.0f / (1.0f + expf(-z));
  }
}

// ----------------------------------------------------------------- launch ---
extern "C" void kernel_launch(void* const* d_in, const int* in_sizes, int n_in,
                              void* d_out, int out_size, void* d_ws, size_t ws_size,
                              hipStream_t stream) {
  const float* x_word = (const float*)d_in[0];
  const float* x_doc  = (const float*)d_in[1];
  const int* src_ww  = (const int*)d_in[2];
  const int* dst_ww  = (const int*)d_in[3];
  const int* src_wd  = (const int*)d_in[4];
  const int* dst_wd  = (const int*)d_in[5];
  const int* src_wwr = (const int*)d_in[6];
  const int* dst_wwr = (const int*)d_in[7];
  const int* src_dwr = (const int*)d_in[8];
  const int* dst_dwr = (const int*)d_in[9];
  const float* W1_ww  = (const float*)d_in[10]; const float* b1_ww  = (const float*)d_in[11];
  const float* W1_wd  = (const float*)d_in[12]; const float* b1_wd  = (const float*)d_in[13];
  const float* W1_wwr = (const float*)d_in[14]; const float* b1_wwr = (const float*)d_in[15];
  const float* W1_dwr = (const float*)d_in[16]; const float* b1_dwr = (const float*)d_in[17];
  const float* W2_ww  = (const float*)d_in[18]; const float* b2_ww  = (const float*)d_in[19];
  const float* W2_wd  = (const float*)d_in[20]; const float* b2_wd  = (const float*)d_in[21];
  const float* W2_wwr = (const float*)d_in[22]; const float* b2_wwr = (const float*)d_in[23];
  const float* W2_dwr = (const float*)d_in[24]; const float* b2_dwr = (const float*)d_in[25];
  const float* lin_w  = (const float*)d_in[26];
  const float* lin_b  = (const float*)d_in[27];
  float* out = (float*)d_out;

  // ---- workspace layout (floats). Zeroed region first, h last (no zero). --
  float* ws = (float*)d_ws;
  size_t off = 0;
  auto alloc = [&](size_t nf) { float* p = ws + off; off += nf; return p; };
  float* rinv_o_ww  = alloc(N_W);
  float* rinv_i_ww  = alloc(N_W);
  float* rinv_o_wd  = alloc(N_W);
  float* rinv_i_wd  = alloc(N_D);
  float* rinv_o_wwr = alloc(N_W);
  float* rinv_i_wwr = alloc(N_W);
  float* rinv_o_dwr = alloc(N_D);
  float* rinv_i_dwr = alloc(N_W);
  const size_t deg_floats = off;  // 340000
  float* accW1 = alloc((size_t)N_W * 128);
  float* accD1 = alloc((size_t)N_D * 128);
  float* accW2 = alloc((size_t)N_W * 128);
  float* accD2 = alloc((size_t)N_D * 128);
  const size_t zero_floats = off;
  float* h = alloc((size_t)N_W * 128);
  (void)ws_size;

  hipMemsetAsync(d_ws, 0, zero_floats * sizeof(float), stream);

  // ---- degrees (shared by both layers) ----
  degree_kernel<<<(E_WW + 255) / 256, 256, 0, stream>>>(src_ww,  dst_ww,  E_WW, rinv_o_ww,  rinv_i_ww);
  degree_kernel<<<(E_WD + 255) / 256, 256, 0, stream>>>(src_wd,  dst_wd,  E_WD, rinv_o_wd,  rinv_i_wd);
  degree_kernel<<<(E_WW + 255) / 256, 256, 0, stream>>>(src_wwr, dst_wwr, E_WW, rinv_o_wwr, rinv_i_wwr);
  degree_kernel<<<(E_WD + 255) / 256, 256, 0, stream>>>(src_dwr, dst_dwr, E_WD, rinv_o_dwr, rinv_i_dwr);
  rsqrt_kernel<<<((int)deg_floats + 255) / 256, 256, 0, stream>>>(ws, (int)deg_floats);

  const dim3 gw((N_W + 63) / 64, 2), gd((N_D + 63) / 64, 2);
  const int sc_ww = (int)(((long long)E_WW * 32 + 255) / 256);
  const int sc_wd = (int)(((long long)E_WD * 32 + 255) / 256);

  // ---- layer 1 (K=256) ----
  gemm_kernel<256><<<gw, 256, 0, stream>>>(x_word, rinv_o_ww, W1_ww, h, N_W);
  scatter_kernel<<<sc_ww, 256, 0, stream>>>(h, src_ww, dst_ww, rinv_i_ww, accW1, E_WW);
  gemm_kernel<256><<<gw, 256, 0, stream>>>(x_word, rinv_o_wwr, W1_wwr, h, N_W);
  scatter_kernel<<<sc_ww, 256, 0, stream>>>(h, src_wwr, dst_wwr, rinv_i_wwr, accW1, E_WW);
  gemm_kernel<256><<<gd, 256, 0, stream>>>(x_doc, rinv_o_dwr, W1_dwr, h, N_D);
  scatter_kernel<<<sc_wd, 256, 0, stream>>>(h, src_dwr, dst_dwr, rinv_i_dwr, accW1, E_WD);
  gemm_kernel<256><<<gw, 256, 0, stream>>>(x_word, rinv_o_wd, W1_wd, h, N_W);
  scatter_kernel<<<sc_wd, 256, 0, stream>>>(h, src_wd, dst_wd, rinv_i_wd, accD1, E_WD);

  finalize_kernel<<<(int)(((long long)N_W * 128 + 255) / 256), 256, 0, stream>>>(
      accW1, b1_ww, b1_wwr, b1_dwr, (long long)N_W * 128);
  finalize_kernel<<<(int)(((long long)N_D * 128 + 255) / 256), 256, 0, stream>>>(
      accD1, b1_wd, nullptr, nullptr, (long long)N_D * 128);

  // ---- layer 2 (K=128) ----
  gemm_kernel<128><<<gw, 256, 0, stream>>>(accW1, rinv_o_ww, W2_ww, h, N_W);
  scatter_kernel<<<sc_ww, 256, 0, stream>>>(h, src_ww, dst_ww, rinv_i_ww, accW2, E_WW);
  gemm_kernel<128><<<gw, 256, 0, stream>>>(accW1, rinv_o_wwr, W2_wwr, h, N_W);
  scatter_kernel<<<sc_ww, 256, 0, stream>>>(h, src_wwr, dst_wwr, rinv_i_wwr, accW2, E_WW);
  gemm_kernel<128><<<gd, 256, 0, stream>>>(accD1, rinv_o_dwr, W2_dwr, h, N_D);
  scatter_kernel<<<sc_wd, 256, 0, stream>>>(h, src_dwr, dst_dwr, rinv_i_dwr, accW2, E_WD);
  gemm_kernel<128><<<gw, 256, 0, stream>>>(accW1, rinv_o_wd, W2_wd, h, N_W);
  scatter_kernel<<<sc_wd, 256, 0, stream>>>(h, src_wd, dst_wd, rinv_i_wd, accD2, E_WD);

  finalize_kernel<<<(int)(((long long)N_W * 128 + 255) / 256), 256, 0, stream>>>(
      accW2, b2_ww, b2_wwr, b2_dwr, (long long)N_W * 128);
  finalize_kernel<<<(int)(((long long)N_D * 128 + 255) / 256), 256, 0, stream>>>(
      accD2, b2_wd, nullptr, nullptr, (long long)N_D * 128);

  // ---- head ----
  final_linear_kernel<<<(N_W + 3) / 4, 256, 0, stream>>>(accW2, lin_w, lin_b, out, N_W);
  final_linear_kernel<<<(N_D + 3) / 4, 256, 0, stream>>>(accD2, lin_w, lin_b, out + N_W, N_D);
}

// Round 2
// 1073.577 us; speedup vs baseline: 5.6616x; 5.6616x over previous
//
#include <hip/hip_runtime.h>
#include <hip/hip_bf16.h>

// GCN_27676769256197 round 2: CSR-gather aggregation (no fp32 atomics),
// bf16 h buffer to halve gather traffic.
//   - per relation: int degree counts (src + dst), exclusive scan of dst
//     counts (single-workgroup, wave-shuffle scan), atomic-cursor CSR fill
//   - gemm: fp32 math, rsqrt(deg_o) from int count in epilogue, bf16 output
//   - gather: 32 lanes/node, register accumulate, rsqrt(deg_i)=f(row length),
//     bias+relu fused into the last relation's gather
//   - head: per-node dot(128) + sigmoid

#define N_W 50000
#define N_D 20000
#define E_WW 500000
#define E_WD 300000

static __device__ __forceinline__ unsigned short f2bf(float x) {
  unsigned u = __float_as_uint(x);
  unsigned r = (u + 0x7fff + ((u >> 16) & 1)) >> 16;  // RNE
  return (unsigned short)r;
}
static __device__ __forceinline__ float bf2f(unsigned short b) {
  return __uint_as_float((unsigned)b << 16);
}

// ----------------------------------------------------------------- counts ---
__global__ __launch_bounds__(256) void count_kernel(
    const int* __restrict__ src, const int* __restrict__ dst, int E,
    int* __restrict__ dego, int* __restrict__ cur) {
  int i = blockIdx.x * 256 + threadIdx.x;
  if (i < E) {
    atomicAdd(&dego[src[i]], 1);
    atomicAdd(&cur[dst[i]], 1);
  }
}

// ---- exclusive scan, in place, 4 arrays in one launch (block per array) ----
__global__ __launch_bounds__(1024) void scan4_kernel(
    int* a0, int n0, int* a1, int n1, int* a2, int n2, int* a3, int n3) {
  int* a; int n;
  switch (blockIdx.x) {
    case 0: a = a0; n = n0; break;
    case 1: a = a1; n = n1; break;
    case 2: a = a2; n = n2; break;
    default: a = a3; n = n3; break;
  }
  __shared__ int wsum[16];
  __shared__ int carry_s;
  const int tid = threadIdx.x;
  const int lane = tid & 63, wave = tid >> 6;
  if (tid == 0) carry_s = 0;
  __syncthreads();
  for (int base = 0; base < n; base += 1024) {
    int idx = base + tid;
    int v = (idx < n) ? a[idx] : 0;
    // inclusive scan within wave
    int s = v;
#pragma unroll
    for (int off = 1; off < 64; off <<= 1) {
      int t = __shfl_up(s, off);
      if (lane >= off) s += t;
    }
    if (lane == 63) wsum[wave] = s;
    __syncthreads();
    int woff = 0;
#pragma unroll
    for (int w = 0; w < 16; w++) woff += (w < wave) ? wsum[w] : 0;
    int excl = carry_s + woff + (s - v);
    if (idx < n) a[idx] = excl;
    __syncthreads();  // all carry_s reads done
    if (tid == 0) {
      int tot = 0;
#pragma unroll
      for (int w = 0; w < 16; w++) tot += wsum[w];
      carry_s += tot;
    }
    __syncthreads();
  }
}

// ------------------------------------------------------------------- fill ---
// after this, cur[n] == end offset of node n (CSR row = [cur[n-1], cur[n]))
__global__ __launch_bounds__(256) void fill_kernel(
    const int* __restrict__ src, const int* __restrict__ dst, int E,
    int* __restrict__ cur, int* __restrict__ csr) {
  int i = blockIdx.x * 256 + threadIdx.x;
  if (i < E) {
    int pos = atomicAdd(&cur[dst[i]], 1);
    csr[pos] = src[i];
  }
}

// ------------------------------------------------------------------- GEMM ---
// h[r][c] = bf16( rsqrt(max(dego[r],1)) * sum_k X[r][k]*W[k][c] )
template <int K>
__global__ __launch_bounds__(256) void gemm_kernel(
    const float* __restrict__ X, const int* __restrict__ dego,
    const float* __restrict__ W, unsigned short* __restrict__ C, int M) {
  __shared__ float Xs[16][64];
  __shared__ float Ws[16][64];
  const int t = threadIdx.x;
  const int tx = t & 15;
  const int ty = t >> 4;
  const int row0 = blockIdx.x * 64;
  const int col0 = blockIdx.y * 64;

  float acc[4][4] = {{0.f}};

  for (int k0 = 0; k0 < K; k0 += 16) {
#pragma unroll
    for (int i = 0; i < 4; i++) {
      int j = t + i * 256;
      int r = j >> 4, kk = j & 15;
      int gr = row0 + r;
      Xs[kk][r] = (gr < M) ? X[(long long)gr * K + (k0 + kk)] : 0.0f;
    }
#pragma unroll
    for (int i = 0; i < 4; i++) {
      int j = t + i * 256;
      int kk = j >> 6, c = j & 63;
      Ws[kk][c] = W[(long long)(k0 + kk) * 128 + col0 + c];
    }
    __syncthreads();
#pragma unroll
    for (int kk = 0; kk < 16; kk++) {
      float4 a = *(const float4*)&Xs[kk][ty * 4];
      float4 b = *(const float4*)&Ws[kk][tx * 4];
      acc[0][0] += a.x * b.x; acc[0][1] += a.x * b.y; acc[0][2] += a.x * b.z; acc[0][3] += a.x * b.w;
      acc[1][0] += a.y * b.x; acc[1][1] += a.y * b.y; acc[1][2] += a.y * b.z; acc[1][3] += a.y * b.w;
      acc[2][0] += a.z * b.x; acc[2][1] += a.z * b.y; acc[2][2] += a.z * b.z; acc[2][3] += a.z * b.w;
      acc[3][0] += a.w * b.x; acc[3][1] += a.w * b.y; acc[3][2] += a.w * b.z; acc[3][3] += a.w * b.w;
    }
    __syncthreads();
  }

#pragma unroll
  for (int i = 0; i < 4; i++) {
    int gr = row0 + ty * 4 + i;
    if (gr >= M) continue;
    float s = rsqrtf(fmaxf((float)dego[gr], 1.0f));
    ushort4 o;
    o.x = f2bf(acc[i][0] * s);
    o.y = f2bf(acc[i][1] * s);
    o.z = f2bf(acc[i][2] * s);
    o.w = f2bf(acc[i][3] * s);
    *(ushort4*)&C[(long long)gr * 128 + col0 + tx * 4] = o;
  }
}

// ----------------------------------------------------------------- gather ---
// 32 lanes per dst node; each lane owns 4 feats (8B bf16 load per edge).
// INIT: first relation for this acc (write, don't read — acc is poisoned).
// FIN:  last relation (add biases, relu).
template <bool INIT, bool FIN>
__global__ __launch_bounds__(256) void gather_kernel(
    const unsigned short* __restrict__ h, const int* __restrict__ csr,
    const int* __restrict__ endoff, float* __restrict__ acc,
    const float* __restrict__ b0, const float* __restrict__ b1,
    const float* __restrict__ b2, int N) {
  int g = blockIdx.x * 8 + (threadIdx.x >> 5);  // node id
  if (g >= N) return;
  int f = (threadIdx.x & 31) * 4;
  int start = (g > 0) ? endoff[g - 1] : 0;
  int end = endoff[g];

  float4 sum = make_float4(0.f, 0.f, 0.f, 0.f);
  for (int j = start; j < end; j++) {
    int s = csr[j];
    ushort4 hv = *(const ushort4*)&h[(long long)s * 128 + f];
    sum.x += bf2f(hv.x);
    sum.y += bf2f(hv.y);
    sum.z += bf2f(hv.z);
    sum.w += bf2f(hv.w);
  }
  float ri = rsqrtf(fmaxf((float)(end - start), 1.0f));
  sum.x *= ri; sum.y *= ri; sum.z *= ri; sum.w *= ri;

  float* ap = &acc[(long long)g * 128 + f];
  float4 v;
  if (INIT) {
    v = sum;
  } else {
    float4 prev = *(const float4*)ap;
    v = make_float4(prev.x + sum.x, prev.y + sum.y, prev.z + sum.z, prev.w + sum.w);
  }
  if (FIN) {
    float bb[4];
#pragma unroll
    for (int i = 0; i < 4; i++) {
      bb[i] = b0[f + i];
      if (b1) bb[i] += b1[f + i];
      if (b2) bb[i] += b2[f + i];
    }
    v.x = fmaxf(v.x + bb[0], 0.f);
    v.y = fmaxf(v.y + bb[1], 0.f);
    v.z = fmaxf(v.z + bb[2], 0.f);
    v.w = fmaxf(v.w + bb[3], 0.f);
  }
  *(float4*)ap = v;
}

// ------------------------------------------------------------------- head ---
__global__ __launch_bounds__(256) void final_linear_kernel(
    const float* __restrict__ X, const float* __restrict__ w,
    const float* __restrict__ b, float* __restrict__ out, int n) {
  int wave = threadIdx.x >> 6;
  int lane = threadIdx.x & 63;
  int node = blockIdx.x * 4 + wave;
  if (node >= n) return;
  const float* xr = X + (long long)node * 128;
  float v = xr[lane] * w[lane] + xr[lane + 64] * w[lane + 64];
#pragma unroll
  for (int off = 32; off > 0; off >>= 1) v += __shfl_down(v, off);
  if (lane == 0) {
    float z = v + b[0];
    out[node] = 1.0f / (1.0f + expf(-z));
  }
}

// ----------------------------------------------------------------- launch ---
extern "C" void kernel_launch(void* const* d_in, const int* in_sizes, int n_in,
                              void* d_out, int out_size, void* d_ws, size_t ws_size,
                              hipStream_t stream) {
  const float* x_word = (const float*)d_in[0];
  const float* x_doc  = (const float*)d_in[1];
  const int* src_ww  = (const int*)d_in[2];
  const int* dst_ww  = (const int*)d_in[3];
  const int* src_wd  = (const int*)d_in[4];
  const int* dst_wd  = (const int*)d_in[5];
  const int* src_wwr = (const int*)d_in[6];
  const int* dst_wwr = (const int*)d_in[7];
  const int* src_dwr = (const int*)d_in[8];
  const int* dst_dwr = (const int*)d_in[9];
  const float* W1_ww  = (const float*)d_in[10]; const float* b1_ww  = (const float*)d_in[11];
  const float* W1_wd  = (const float*)d_in[12]; const float* b1_wd  = (const float*)d_in[13];
  const float* W1_wwr = (const float*)d_in[14]; const float* b1_wwr = (const float*)d_in[15];
  const float* W1_dwr = (const float*)d_in[16]; const float* b1_dwr = (const float*)d_in[17];
  const float* W2_ww  = (const float*)d_in[18]; const float* b2_ww  = (const float*)d_in[19];
  const float* W2_wd  = (const float*)d_in[20]; const float* b2_wd  = (const float*)d_in[21];
  const float* W2_wwr = (const float*)d_in[22]; const float* b2_wwr = (const float*)d_in[23];
  const float* W2_dwr = (const float*)d_in[24]; const float* b2_dwr = (const float*)d_in[25];
  const float* lin_w  = (const float*)d_in[26];
  const float* lin_b  = (const float*)d_in[27];
  float* out = (float*)d_out;

  // ---- workspace layout (4-byte units) ----
  char* ws = (char*)d_ws;
  size_t off = 0;
  auto alloc = [&](size_t n4) { void* p = ws + off * 4; off += n4; return p; };
  // zeroed region: dst cursors + src degrees
  int* cur_ww   = (int*)alloc(N_W);
  int* cur_wwr  = (int*)alloc(N_W);
  int* cur_wd   = (int*)alloc(N_D);
  int* cur_dwr  = (int*)alloc(N_W);
  int* dego_ww  = (int*)alloc(N_W);
  int* dego_wwr = (int*)alloc(N_W);
  int* dego_wd  = (int*)alloc(N_W);
  int* dego_dwr = (int*)alloc(N_D);
  const size_t zero4 = off;  // 340000 ints
  int* csr_ww   = (int*)alloc(E_WW);
  int* csr_wwr  = (int*)alloc(E_WW);
  int* csr_wd   = (int*)alloc(E_WD);
  int* csr_dwr  = (int*)alloc(E_WD);
  float* accW1 = (float*)alloc((size_t)N_W * 128);
  float* accD1 = (float*)alloc((size_t)N_D * 128);
  float* accW2 = (float*)alloc((size_t)N_W * 128);
  float* accD2 = (float*)alloc((size_t)N_D * 128);
  unsigned short* h = (unsigned short*)alloc((size_t)N_W * 128 / 2);
  (void)ws_size;

  hipMemsetAsync(d_ws, 0, zero4 * 4, stream);

  // ---- CSR build (once, reused by both layers) ----
  const int gE_ww = (E_WW + 255) / 256, gE_wd = (E_WD + 255) / 256;
  count_kernel<<<gE_ww, 256, 0, stream>>>(src_ww,  dst_ww,  E_WW, dego_ww,  cur_ww);
  count_kernel<<<gE_ww, 256, 0, stream>>>(src_wwr, dst_wwr, E_WW, dego_wwr, cur_wwr);
  count_kernel<<<gE_wd, 256, 0, stream>>>(src_wd,  dst_wd,  E_WD, dego_wd,  cur_wd);
  count_kernel<<<gE_wd, 256, 0, stream>>>(src_dwr, dst_dwr, E_WD, dego_dwr, cur_dwr);
  scan4_kernel<<<4, 1024, 0, stream>>>(cur_ww, N_W, cur_wwr, N_W, cur_wd, N_D, cur_dwr, N_W);
  fill_kernel<<<gE_ww, 256, 0, stream>>>(src_ww,  dst_ww,  E_WW, cur_ww,  csr_ww);
  fill_kernel<<<gE_ww, 256, 0, stream>>>(src_wwr, dst_wwr, E_WW, cur_wwr, csr_wwr);
  fill_kernel<<<gE_wd, 256, 0, stream>>>(src_wd,  dst_wd,  E_WD, cur_wd,  csr_wd);
  fill_kernel<<<gE_wd, 256, 0, stream>>>(src_dwr, dst_dwr, E_WD, cur_dwr, csr_dwr);

  const dim3 gw((N_W + 63) / 64, 2), gd((N_D + 63) / 64, 2);
  const int ggW = (N_W + 7) / 8, ggD = (N_D + 7) / 8;

  // ---- layer 1 (K=256) ----
  gemm_kernel<256><<<gw, 256, 0, stream>>>(x_word, dego_ww, W1_ww, h, N_W);
  gather_kernel<true, false><<<ggW, 256, 0, stream>>>(h, csr_ww, cur_ww, accW1, nullptr, nullptr, nullptr, N_W);
  gemm_kernel<256><<<gw, 256, 0, stream>>>(x_word, dego_wwr, W1_wwr, h, N_W);
  gather_kernel<false, false><<<ggW, 256, 0, stream>>>(h, csr_wwr, cur_wwr, accW1, nullptr, nullptr, nullptr, N_W);
  gemm_kernel<256><<<gd, 256, 0, stream>>>(x_doc, dego_dwr, W1_dwr, h, N_D);
  gather_kernel<false, true><<<ggW, 256, 0, stream>>>(h, csr_dwr, cur_dwr, accW1, b1_ww, b1_wwr, b1_dwr, N_W);
  gemm_kernel<256><<<gw, 256, 0, stream>>>(x_word, dego_wd, W1_wd, h, N_W);
  gather_kernel<true, true><<<ggD, 256, 0, stream>>>(h, csr_wd, cur_wd, accD1, b1_wd, nullptr, nullptr, N_D);

  // ---- layer 2 (K=128) ----
  gemm_kernel<128><<<gw, 256, 0, stream>>>(accW1, dego_ww, W2_ww, h, N_W);
  gather_kernel<true, false><<<ggW, 256, 0, stream>>>(h, csr_ww, cur_ww, accW2, nullptr, nullptr, nullptr, N_W);
  gemm_kernel<128><<<gw, 256, 0, stream>>>(accW1, dego_wwr, W2_wwr, h, N_W);
  gather_kernel<false, false><<<ggW, 256, 0, stream>>>(h, csr_wwr, cur_wwr, accW2, nullptr, nullptr, nullptr, N_W);
  gemm_kernel<128><<<gd, 256, 0, stream>>>(accD1, dego_dwr, W2_dwr, h, N_D);
  gather_kernel<false, true><<<ggW, 256, 0, stream>>>(h, csr_dwr, cur_dwr, accW2, b2_ww, b2_wwr, b2_dwr, N_W);
  gemm_kernel<128><<<gw, 256, 0, stream>>>(accW1, dego_wd, W2_wd, h, N_W);
  gather_kernel<true, true><<<ggD, 256, 0, stream>>>(h, csr_wd, cur_wd, accD2, b2_wd, nullptr, nullptr, N_D);

  // ---- head ----
  final_linear_kernel<<<(N_W + 3) / 4, 256, 0, stream>>>(accW2, lin_w, lin_b, out, N_W);
  final_linear_kernel<<<(N_D + 3) / 4, 256, 0, stream>>>(accD2, lin_w, lin_b, out + N_W, N_D);
}

// Round 3
// 737.290 us; speedup vs baseline: 8.2439x; 1.4561x over previous
//
#include <hip/hip_runtime.h>
#include <hip/hip_bf16.h>

// GCN_27676769256197 round 3:
//   - bf16 MFMA GEMM (16x16x32), fp32->bf16 conversion fused into LDS staging,
//     fragment-ready LDS layout (8-elem chunks, ds_read_b128, conflict-free).
//     3 word-relation GEMMs merged into one dispatch (blockIdx.y = relation),
//     output h_w3 [N_W x 384] bf16; deg_o scale in epilogue.
//   - all GEMMs of a layer run before the gathers; gathers fused per dst:
//     gather3 (ww+wwr+dwr -> accW, bias+relu), gather1 (wd -> accD).
//     accW2 aliases accW1 (dead after layer-2 GEMMs read it).
//   - CSR build unchanged from round 2.

#define N_W 50000
#define N_D 20000
#define E_WW 500000
#define E_WD 300000

typedef __attribute__((ext_vector_type(8))) short short8;
typedef __attribute__((ext_vector_type(4))) float f32x4;

static __device__ __forceinline__ unsigned f2bf_u(float x) {
  unsigned u = __float_as_uint(x);
  return (u + 0x7fff + ((u >> 16) & 1)) >> 16;  // RNE
}
static __device__ __forceinline__ unsigned short f2bf(float x) {
  return (unsigned short)f2bf_u(x);
}
static __device__ __forceinline__ float bf2f(unsigned short b) {
  return __uint_as_float((unsigned)b << 16);
}

// ----------------------------------------------------------------- counts ---
__global__ __launch_bounds__(256) void count_kernel(
    const int* __restrict__ src, const int* __restrict__ dst, int E,
    int* __restrict__ dego, int* __restrict__ cur) {
  int i = blockIdx.x * 256 + threadIdx.x;
  if (i < E) {
    atomicAdd(&dego[src[i]], 1);
    atomicAdd(&cur[dst[i]], 1);
  }
}

// ---- exclusive scan, in place, 4 arrays in one launch (block per array) ----
__global__ __launch_bounds__(1024) void scan4_kernel(
    int* a0, int n0, int* a1, int n1, int* a2, int n2, int* a3, int n3) {
  int* a; int n;
  switch (blockIdx.x) {
    case 0: a = a0; n = n0; break;
    case 1: a = a1; n = n1; break;
    case 2: a = a2; n = n2; break;
    default: a = a3; n = n3; break;
  }
  __shared__ int wsum[16];
  __shared__ int carry_s;
  const int tid = threadIdx.x;
  const int lane = tid & 63, wave = tid >> 6;
  if (tid == 0) carry_s = 0;
  __syncthreads();
  for (int base = 0; base < n; base += 1024) {
    int idx = base + tid;
    int v = (idx < n) ? a[idx] : 0;
    int s = v;
#pragma unroll
    for (int off = 1; off < 64; off <<= 1) {
      int t = __shfl_up(s, off);
      if (lane >= off) s += t;
    }
    if (lane == 63) wsum[wave] = s;
    __syncthreads();
    int woff = 0;
#pragma unroll
    for (int w = 0; w < 16; w++) woff += (w < wave) ? wsum[w] : 0;
    int excl = carry_s + woff + (s - v);
    if (idx < n) a[idx] = excl;
    __syncthreads();
    if (tid == 0) {
      int tot = 0;
#pragma unroll
      for (int w = 0; w < 16; w++) tot += wsum[w];
      carry_s += tot;
    }
    __syncthreads();
  }
}

// ------------------------------------------------------------------- fill ---
__global__ __launch_bounds__(256) void fill_kernel(
    const int* __restrict__ src, const int* __restrict__ dst, int E,
    int* __restrict__ cur, int* __restrict__ csr) {
  int i = blockIdx.x * 256 + threadIdx.x;
  if (i < E) {
    int pos = atomicAdd(&cur[dst[i]], 1);
    csr[pos] = src[i];
  }
}

// -------------------------------------------------------------- MFMA GEMM ---
// C[r][col0+c] = bf16( rsqrt(max(dego[r],1)) * sum_k A[r][k]*B[k][c] )
// A: [M x K] fp32, B: [K x 128] fp32 (selected by blockIdx.y), C bf16 stride
// cstride. Block 128x128, 4 waves of 64x64 (4x4 tiles of 16x16x32 MFMA).
// LDS fragment-ready: chunk(q,r) = 8 bf16 (k = q*8..+7) at q*2064 + r*16.
template <int K>
__global__ __launch_bounds__(256) void mfma_gemm_kernel(
    const float* __restrict__ A, int M,
    const float* __restrict__ B0, const float* __restrict__ B1,
    const float* __restrict__ B2,
    const int* __restrict__ d0, const int* __restrict__ d1,
    const int* __restrict__ d2,
    unsigned short* __restrict__ C, int cstride) {
  const int cb = blockIdx.y;
  const float* __restrict__ B = (cb == 0) ? B0 : ((cb == 1) ? B1 : B2);
  const int* __restrict__ dego = (cb == 0) ? d0 : ((cb == 1) ? d1 : d2);
  const int row0 = blockIdx.x * 128;

  const int tid = threadIdx.x;
  const int lane = tid & 63;
  const int wave = tid >> 6;
  const int wr = wave >> 1;        // wave row (0..1) -> rows wr*64
  const int wc = wave & 1;         // wave col (0..1) -> cols wc*64
  const int lc = lane & 15;        // fragment col/row index
  const int quad = lane >> 4;      // 0..3

  // LDS: A region [0, 16512), B region [16512, 33024). chunk stride 2064 B.
  __shared__ __align__(16) unsigned char smem[33024];
  unsigned char* sA = smem;
  unsigned char* sB = smem + 16512;

  f32x4 acc[4][4];
#pragma unroll
  for (int a = 0; a < 4; a++)
#pragma unroll
    for (int b = 0; b < 4; b++) acc[a][b] = {0.f, 0.f, 0.f, 0.f};

  for (int k0 = 0; k0 < K; k0 += 64) {
    // ---- stage A: 128 rows x 64 k fp32 -> bf16 chunks ----
#pragma unroll
    for (int i = 0; i < 8; i++) {
      int f = tid + i * 256;           // float4 id, 0..2047
      int r = f >> 4;                  // 0..127
      int kq = f & 15;                 // float4 within row (4 k each)
      int grow = row0 + r;
      float4 v = make_float4(0.f, 0.f, 0.f, 0.f);
      if (grow < M) v = *(const float4*)(A + (size_t)grow * K + k0 + kq * 4);
      uint2 p;
      p.x = f2bf_u(v.x) | (f2bf_u(v.y) << 16);
      p.y = f2bf_u(v.z) | (f2bf_u(v.w) << 16);
      *(uint2*)(sA + (kq >> 1) * 2064 + r * 16 + (kq & 1) * 8) = p;
    }
    // ---- stage B: 64 k x 128 cols fp32 -> bf16 chunks (column gather) ----
#pragma unroll
    for (int i = 0; i < 4; i++) {
      int c = tid + i * 256;           // chunk id, 0..1023
      int n = c & 127, q = c >> 7;
      const float* bp = B + (size_t)(k0 + q * 8) * 128 + n;
      float t0 = bp[0 * 128], t1 = bp[1 * 128], t2 = bp[2 * 128], t3 = bp[3 * 128];
      float t4 = bp[4 * 128], t5 = bp[5 * 128], t6 = bp[6 * 128], t7 = bp[7 * 128];
      uint4 p;
      p.x = f2bf_u(t0) | (f2bf_u(t1) << 16);
      p.y = f2bf_u(t2) | (f2bf_u(t3) << 16);
      p.z = f2bf_u(t4) | (f2bf_u(t5) << 16);
      p.w = f2bf_u(t6) | (f2bf_u(t7) << 16);
      *(uint4*)(sB + q * 2064 + n * 16) = p;
    }
    __syncthreads();

    // ---- MFMA: 2 k32-steps x 4x4 tiles ----
#pragma unroll
    for (int s = 0; s < 2; s++) {
      int qoff = (s * 4 + quad) * 2064 + lc * 16;
      short8 av[4], bv[4];
#pragma unroll
      for (int a = 0; a < 4; a++)
        av[a] = *(const short8*)(sA + qoff + (wr * 64 + a * 16) * 16);
#pragma unroll
      for (int b = 0; b < 4; b++)
        bv[b] = *(const short8*)(sB + qoff + (wc * 64 + b * 16) * 16);
#pragma unroll
      for (int a = 0; a < 4; a++)
#pragma unroll
        for (int b = 0; b < 4; b++)
          acc[a][b] = __builtin_amdgcn_mfma_f32_16x16x32_bf16(
              av[a], bv[b], acc[a][b], 0, 0, 0);
    }
    __syncthreads();
  }

  // ---- epilogue: scale by rsqrt(deg_o), store bf16 ----
  const int colb = cb * 128 + wc * 64;
#pragma unroll
  for (int a = 0; a < 4; a++) {
#pragma unroll
    for (int i = 0; i < 4; i++) {
      int r = row0 + wr * 64 + a * 16 + quad * 4 + i;
      if (r >= M) continue;
      float sc = rsqrtf(fmaxf((float)dego[r], 1.0f));
      unsigned short* cp = C + (size_t)r * cstride + colb + lc;
#pragma unroll
      for (int b = 0; b < 4; b++) cp[b * 16] = f2bf(acc[a][b][i] * sc);
    }
  }
}

// ---------------------------------------------------------------- gathers ---
static __device__ __forceinline__ float4 edge_sum(
    const unsigned short* __restrict__ base, int stride,
    const int* __restrict__ csr, int st, int en) {
  float4 s0 = make_float4(0.f, 0.f, 0.f, 0.f);
  float4 s1 = make_float4(0.f, 0.f, 0.f, 0.f);
  int j = st;
  for (; j + 1 < en; j += 2) {
    int a = csr[j], b = csr[j + 1];
    ushort4 u0 = *(const ushort4*)(base + (size_t)a * stride);
    ushort4 u1 = *(const ushort4*)(base + (size_t)b * stride);
    s0.x += bf2f(u0.x); s0.y += bf2f(u0.y); s0.z += bf2f(u0.z); s0.w += bf2f(u0.w);
    s1.x += bf2f(u1.x); s1.y += bf2f(u1.y); s1.z += bf2f(u1.z); s1.w += bf2f(u1.w);
  }
  if (j < en) {
    int a = csr[j];
    ushort4 u0 = *(const ushort4*)(base + (size_t)a * stride);
    s0.x += bf2f(u0.x); s0.y += bf2f(u0.y); s0.z += bf2f(u0.z); s0.w += bf2f(u0.w);
  }
  return make_float4(s0.x + s1.x, s0.y + s1.y, s0.z + s1.z, s0.w + s1.w);
}

// word dst: ww (hw cols 0-127) + wwr (hw cols 128-255) + dwr (hd) -> acc, relu
__global__ __launch_bounds__(256) void gather3_kernel(
    const unsigned short* __restrict__ hw, const unsigned short* __restrict__ hd,
    const int* __restrict__ e1, const int* __restrict__ e2,
    const int* __restrict__ e3,
    const int* __restrict__ c1, const int* __restrict__ c2,
    const int* __restrict__ c3,
    const float* __restrict__ b0, const float* __restrict__ b1,
    const float* __restrict__ b2, float* __restrict__ acc) {
  int g = blockIdx.x * 8 + (threadIdx.x >> 5);
  if (g >= N_W) return;
  int f = (threadIdx.x & 31) * 4;

  int st1 = g ? e1[g - 1] : 0, en1 = e1[g];
  int st2 = g ? e2[g - 1] : 0, en2 = e2[g];
  int st3 = g ? e3[g - 1] : 0, en3 = e3[g];
  float4 s1 = edge_sum(hw + f, 384, c1, st1, en1);
  float4 s2 = edge_sum(hw + 128 + f, 384, c2, st2, en2);
  float4 s3 = edge_sum(hd + f, 128, c3, st3, en3);
  float r1 = rsqrtf(fmaxf((float)(en1 - st1), 1.f));
  float r2 = rsqrtf(fmaxf((float)(en2 - st2), 1.f));
  float r3 = rsqrtf(fmaxf((float)(en3 - st3), 1.f));

  float* ap = acc + (size_t)g * 128 + f;
#pragma unroll
  for (int i = 0; i < 4; i++) {
    float bb = b0[f + i] + b1[f + i] + b2[f + i];
    float v = (&s1.x)[i] * r1 + (&s2.x)[i] * r2 + (&s3.x)[i] * r3 + bb;
    ap[i] = fmaxf(v, 0.f);
  }
}

// doc dst: wd (hw cols 256-383) -> acc, relu
__global__ __launch_bounds__(256) void gather1_kernel(
    const unsigned short* __restrict__ hw, const int* __restrict__ e1,
    const int* __restrict__ c1, const float* __restrict__ b0,
    float* __restrict__ acc) {
  int g = blockIdx.x * 8 + (threadIdx.x >> 5);
  if (g >= N_D) return;
  int f = (threadIdx.x & 31) * 4;
  int st1 = g ? e1[g - 1] : 0, en1 = e1[g];
  float4 s1 = edge_sum(hw + 256 + f, 384, c1, st1, en1);
  float r1 = rsqrtf(fmaxf((float)(en1 - st1), 1.f));
  float* ap = acc + (size_t)g * 128 + f;
#pragma unroll
  for (int i = 0; i < 4; i++) ap[i] = fmaxf((&s1.x)[i] * r1 + b0[f + i], 0.f);
}

// ------------------------------------------------------------------- head ---
__global__ __launch_bounds__(256) void final_linear_kernel(
    const float* __restrict__ X, const float* __restrict__ w,
    const float* __restrict__ b, float* __restrict__ out, int n) {
  int wave = threadIdx.x >> 6;
  int lane = threadIdx.x & 63;
  int node = blockIdx.x * 4 + wave;
  if (node >= n) return;
  const float* xr = X + (size_t)node * 128;
  float v = xr[lane] * w[lane] + xr[lane + 64] * w[lane + 64];
#pragma unroll
  for (int off = 32; off > 0; off >>= 1) v += __shfl_down(v, off);
  if (lane == 0) {
    float z = v + b[0];
    out[node] = 1.0f / (1.0f + expf(-z));
  }
}

// ----------------------------------------------------------------- launch ---
extern "C" void kernel_launch(void* const* d_in, const int* in_sizes, int n_in,
                              void* d_out, int out_size, void* d_ws, size_t ws_size,
                              hipStream_t stream) {
  const float* x_word = (const float*)d_in[0];
  const float* x_doc  = (const float*)d_in[1];
  const int* src_ww  = (const int*)d_in[2];
  const int* dst_ww  = (const int*)d_in[3];
  const int* src_wd  = (const int*)d_in[4];
  const int* dst_wd  = (const int*)d_in[5];
  const int* src_wwr = (const int*)d_in[6];
  const int* dst_wwr = (const int*)d_in[7];
  const int* src_dwr = (const int*)d_in[8];
  const int* dst_dwr = (const int*)d_in[9];
  const float* W1_ww  = (const float*)d_in[10]; const float* b1_ww  = (const float*)d_in[11];
  const float* W1_wd  = (const float*)d_in[12]; const float* b1_wd  = (const float*)d_in[13];
  const float* W1_wwr = (const float*)d_in[14]; const float* b1_wwr = (const float*)d_in[15];
  const float* W1_dwr = (const float*)d_in[16]; const float* b1_dwr = (const float*)d_in[17];
  const float* W2_ww  = (const float*)d_in[18]; const float* b2_ww  = (const float*)d_in[19];
  const float* W2_wd  = (const float*)d_in[20]; const float* b2_wd  = (const float*)d_in[21];
  const float* W2_wwr = (const float*)d_in[22]; const float* b2_wwr = (const float*)d_in[23];
  const float* W2_dwr = (const float*)d_in[24]; const float* b2_dwr = (const float*)d_in[25];
  const float* lin_w  = (const float*)d_in[26];
  const float* lin_b  = (const float*)d_in[27];
  float* out = (float*)d_out;

  // ---- workspace layout (4-byte units) ----
  char* ws = (char*)d_ws;
  size_t off = 0;
  auto alloc = [&](size_t n4) { void* p = ws + off * 4; off += n4; return p; };
  int* cur_ww   = (int*)alloc(N_W);
  int* cur_wwr  = (int*)alloc(N_W);
  int* cur_wd   = (int*)alloc(N_D);
  int* cur_dwr  = (int*)alloc(N_W);
  int* dego_ww  = (int*)alloc(N_W);
  int* dego_wwr = (int*)alloc(N_W);
  int* dego_wd  = (int*)alloc(N_W);
  int* dego_dwr = (int*)alloc(N_D);
  const size_t zero4 = off;  // 340000 ints
  int* csr_ww   = (int*)alloc(E_WW);
  int* csr_wwr  = (int*)alloc(E_WW);
  int* csr_wd   = (int*)alloc(E_WD);
  int* csr_dwr  = (int*)alloc(E_WD);
  float* accW = (float*)alloc((size_t)N_W * 128);   // layer1 out, layer2 out (aliased)
  float* accD = (float*)alloc((size_t)N_D * 128);
  unsigned short* h_w3 = (unsigned short*)alloc((size_t)N_W * 384 / 2);  // ww|wwr|wd
  unsigned short* h_d  = (unsigned short*)alloc((size_t)N_D * 128 / 2);  // dwr
  (void)ws_size;

  hipMemsetAsync(d_ws, 0, zero4 * 4, stream);

  // ---- CSR build (once, reused by both layers) ----
  const int gE_ww = (E_WW + 255) / 256, gE_wd = (E_WD + 255) / 256;
  count_kernel<<<gE_ww, 256, 0, stream>>>(src_ww,  dst_ww,  E_WW, dego_ww,  cur_ww);
  count_kernel<<<gE_ww, 256, 0, stream>>>(src_wwr, dst_wwr, E_WW, dego_wwr, cur_wwr);
  count_kernel<<<gE_wd, 256, 0, stream>>>(src_wd,  dst_wd,  E_WD, dego_wd,  cur_wd);
  count_kernel<<<gE_wd, 256, 0, stream>>>(src_dwr, dst_dwr, E_WD, dego_dwr, cur_dwr);
  scan4_kernel<<<4, 1024, 0, stream>>>(cur_ww, N_W, cur_wwr, N_W, cur_wd, N_D, cur_dwr, N_W);
  fill_kernel<<<gE_ww, 256, 0, stream>>>(src_ww,  dst_ww,  E_WW, cur_ww,  csr_ww);
  fill_kernel<<<gE_ww, 256, 0, stream>>>(src_wwr, dst_wwr, E_WW, cur_wwr, csr_wwr);
  fill_kernel<<<gE_wd, 256, 0, stream>>>(src_wd,  dst_wd,  E_WD, cur_wd,  csr_wd);
  fill_kernel<<<gE_wd, 256, 0, stream>>>(src_dwr, dst_dwr, E_WD, cur_dwr, csr_dwr);

  const dim3 gw((N_W + 127) / 128, 3);   // word GEMM: 3 relations
  const dim3 gd((N_D + 127) / 128, 1);   // doc GEMM (dwr)
  const int ggW = (N_W + 7) / 8, ggD = (N_D + 7) / 8;

  // ---- layer 1 (K=256): all GEMMs, then fused gathers ----
  mfma_gemm_kernel<256><<<gw, 256, 0, stream>>>(
      x_word, N_W, W1_ww, W1_wwr, W1_wd, dego_ww, dego_wwr, dego_wd, h_w3, 384);
  mfma_gemm_kernel<256><<<gd, 256, 0, stream>>>(
      x_doc, N_D, W1_dwr, W1_dwr, W1_dwr, dego_dwr, dego_dwr, dego_dwr, h_d, 128);
  gather3_kernel<<<ggW, 256, 0, stream>>>(
      h_w3, h_d, cur_ww, cur_wwr, cur_dwr, csr_ww, csr_wwr, csr_dwr,
      b1_ww, b1_wwr, b1_dwr, accW);
  gather1_kernel<<<ggD, 256, 0, stream>>>(h_w3, cur_wd, csr_wd, b1_wd, accD);

  // ---- layer 2 (K=128): GEMMs read accW/accD, then gathers overwrite them --
  mfma_gemm_kernel<128><<<gw, 256, 0, stream>>>(
      accW, N_W, W2_ww, W2_wwr, W2_wd, dego_ww, dego_wwr, dego_wd, h_w3, 384);
  mfma_gemm_kernel<128><<<gd, 256, 0, stream>>>(
      accD, N_D, W2_dwr, W2_dwr, W2_dwr, dego_dwr, dego_dwr, dego_dwr, h_d, 128);
  gather3_kernel<<<ggW, 256, 0, stream>>>(
      h_w3, h_d, cur_ww, cur_wwr, cur_dwr, csr_ww, csr_wwr, csr_dwr,
      b2_ww, b2_wwr, b2_dwr, accW);
  gather1_kernel<<<ggD, 256, 0, stream>>>(h_w3, cur_wd, csr_wd, b2_wd, accD);

  // ---- head ----
  final_linear_kernel<<<(N_W + 3) / 4, 256, 0, stream>>>(accW, lin_w, lin_b, out, N_W);
  final_linear_kernel<<<(N_D + 3) / 4, 256, 0, stream>>>(accD, lin_w, lin_b, out + N_W, N_D);
}

// Round 4
// 653.235 us; speedup vs baseline: 9.3047x; 1.1287x over previous
//
#include <hip/hip_runtime.h>
#include <hip/hip_bf16.h>

// GCN_27676769256197 round 4:
//   - activations/weights pre-converted to bf16 once; weights packed B^T [N][K]
//   - GEMM: global_load_lds width=16 staging (m97 pattern), ds_read_b128 frags,
//     16x16x32 bf16 MFMA, 128x128 block tile, deg_o scale in epilogue
//   - gathers: cooperative csr index loads (shfl broadcast), 4-deep unroll,
//     L1 writes bf16 acc (feeds L2 GEMM directly), L2 gathers fuse the
//     sigmoid head and write d_out (no acc2 buffers, no head kernels)
//   - CSR build unchanged (proven)

#define N_W 50000
#define N_D 20000
#define E_WW 500000
#define E_WD 300000

typedef __attribute__((ext_vector_type(8))) short short8;
typedef __attribute__((ext_vector_type(4))) float f32x4;

static __device__ __forceinline__ unsigned f2bf_u(float x) {
  unsigned u = __float_as_uint(x);
  return (u + 0x7fff + ((u >> 16) & 1)) >> 16;  // RNE
}
static __device__ __forceinline__ unsigned short f2bf(float x) {
  return (unsigned short)f2bf_u(x);
}
static __device__ __forceinline__ float bf2f(unsigned short b) {
  return __uint_as_float((unsigned)b << 16);
}

static __device__ __forceinline__ void gld16(const void* g, void* l) {
  __builtin_amdgcn_global_load_lds(
      (const __attribute__((address_space(1))) void*)g,
      (__attribute__((address_space(3))) void*)l, 16, 0, 0);
}

// ----------------------------------------------------------------- counts ---
__global__ __launch_bounds__(256) void count_kernel(
    const int* __restrict__ src, const int* __restrict__ dst, int E,
    int* __restrict__ dego, int* __restrict__ cur) {
  int i = blockIdx.x * 256 + threadIdx.x;
  if (i < E) {
    atomicAdd(&dego[src[i]], 1);
    atomicAdd(&cur[dst[i]], 1);
  }
}

// ---- exclusive scan, in place, 4 arrays in one launch (block per array) ----
__global__ __launch_bounds__(1024) void scan4_kernel(
    int* a0, int n0, int* a1, int n1, int* a2, int n2, int* a3, int n3) {
  int* a; int n;
  switch (blockIdx.x) {
    case 0: a = a0; n = n0; break;
    case 1: a = a1; n = n1; break;
    case 2: a = a2; n = n2; break;
    default: a = a3; n = n3; break;
  }
  __shared__ int wsum[16];
  __shared__ int carry_s;
  const int tid = threadIdx.x;
  const int lane = tid & 63, wave = tid >> 6;
  if (tid == 0) carry_s = 0;
  __syncthreads();
  for (int base = 0; base < n; base += 1024) {
    int idx = base + tid;
    int v = (idx < n) ? a[idx] : 0;
    int s = v;
#pragma unroll
    for (int off = 1; off < 64; off <<= 1) {
      int t = __shfl_up(s, off);
      if (lane >= off) s += t;
    }
    if (lane == 63) wsum[wave] = s;
    __syncthreads();
    int woff = 0;
#pragma unroll
    for (int w = 0; w < 16; w++) woff += (w < wave) ? wsum[w] : 0;
    int excl = carry_s + woff + (s - v);
    if (idx < n) a[idx] = excl;
    __syncthreads();
    if (tid == 0) {
      int tot = 0;
#pragma unroll
      for (int w = 0; w < 16; w++) tot += wsum[w];
      carry_s += tot;
    }
    __syncthreads();
  }
}

// ------------------------------------------------------------------- fill ---
__global__ __launch_bounds__(256) void fill_kernel(
    const int* __restrict__ src, const int* __restrict__ dst, int E,
    int* __restrict__ cur, int* __restrict__ csr) {
  int i = blockIdx.x * 256 + threadIdx.x;
  if (i < E) {
    int pos = atomicAdd(&cur[dst[i]], 1);
    csr[pos] = src[i];
  }
}

// --------------------------------------------------------------- converts ---
__global__ __launch_bounds__(256) void cvt_bf16_kernel(
    const float* __restrict__ x, unsigned short* __restrict__ y, int n4) {
  int i = blockIdx.x * 256 + threadIdx.x;
  if (i < n4) {
    float4 v = ((const float4*)x)[i];
    ushort4 u;
    u.x = f2bf(v.x); u.y = f2bf(v.y); u.z = f2bf(v.z); u.w = f2bf(v.w);
    ((ushort4*)y)[i] = u;
  }
}

// out[n*K + k] = bf16(Wsel[k][n&127]) — packed transposed weights, N=128*nrel
__global__ __launch_bounds__(256) void packB_kernel(
    const float* __restrict__ W0, const float* __restrict__ W1,
    const float* __restrict__ W2, int K, int N, unsigned short* __restrict__ out) {
  int i = blockIdx.x * 256 + threadIdx.x;
  if (i >= N * K) return;
  int n = i / K, k = i - n * K;
  const float* W = (n < 128) ? W0 : ((n < 256) ? W1 : W2);
  out[i] = f2bf(W[(size_t)k * 128 + (n & 127)]);
}

// -------------------------------------------------------------- MFMA GEMM ---
// C[r][cb*128+c] = bf16( rsqrt(max(dego[r],1)) * sum_k A[r][k]*Bt[cb*128+c][k] )
// A: [M x K] bf16 row-major; Bt: [N x K] bf16 (B transposed). Block 128x128,
// 4 waves of 64x64. Staging via global_load_lds (16B/lane, packed chunks):
// LDS region per operand: chunk(kc,m) at kc*2048 + m*16 (kc=k/8, m=row|col).
template <int K>
__global__ __launch_bounds__(256) void mfma_gemm_kernel(
    const unsigned short* __restrict__ A, int M,
    const unsigned short* __restrict__ Bt,
    const int* __restrict__ d0, const int* __restrict__ d1,
    const int* __restrict__ d2,
    unsigned short* __restrict__ C, int cstride) {
  const int cb = blockIdx.y;
  const int* __restrict__ dego = (cb == 0) ? d0 : ((cb == 1) ? d1 : d2);
  const int row0 = blockIdx.x * 128;

  const int tid = threadIdx.x;
  const int lane = tid & 63;
  const int wave = tid >> 6;
  const int wr = wave >> 1;
  const int wc = wave & 1;
  const int lc = lane & 15;
  const int quad = lane >> 4;

  __shared__ __align__(16) unsigned char smem[32768];
  unsigned char* sA = smem;
  unsigned char* sB = smem + 16384;

  // staging source rows (per thread): thread t covers chunk m = t&127,
  // kc = i*2 + (t>>7) for issues i=0..3; LDS dest base wave-uniform.
  const int mn = tid & 127;
  const int kc0 = tid >> 7;
  const unsigned short* arow = A + (size_t)(row0 + mn) * K;
  const unsigned short* brow = Bt + (size_t)(cb * 128 + mn) * K;
  unsigned char* ldsA = sA + wave * 1024;
  unsigned char* ldsB = sB + wave * 1024;

  f32x4 acc[4][4];
#pragma unroll
  for (int a = 0; a < 4; a++)
#pragma unroll
    for (int b = 0; b < 4; b++) acc[a][b] = {0.f, 0.f, 0.f, 0.f};

  for (int k0 = 0; k0 < K; k0 += 64) {
#pragma unroll
    for (int i = 0; i < 4; i++) {
      int kk = k0 + (i * 2 + kc0) * 8;
      gld16(arow + kk, ldsA + i * 4096);
      gld16(brow + kk, ldsB + i * 4096);
    }
    __syncthreads();
#pragma unroll
    for (int s = 0; s < 2; s++) {
      const int ko = (s * 4 + quad) * 2048 + lc * 16;
      short8 av[4], bv[4];
#pragma unroll
      for (int a = 0; a < 4; a++)
        av[a] = *(const short8*)(sA + ko + (wr * 64 + a * 16) * 16);
#pragma unroll
      for (int b = 0; b < 4; b++)
        bv[b] = *(const short8*)(sB + ko + (wc * 64 + b * 16) * 16);
#pragma unroll
      for (int a = 0; a < 4; a++)
#pragma unroll
        for (int b = 0; b < 4; b++)
          acc[a][b] = __builtin_amdgcn_mfma_f32_16x16x32_bf16(
              av[a], bv[b], acc[a][b], 0, 0, 0);
    }
    __syncthreads();
  }

  const int colb = cb * 128 + wc * 64;
#pragma unroll
  for (int a = 0; a < 4; a++) {
#pragma unroll
    for (int i = 0; i < 4; i++) {
      int r = row0 + wr * 64 + a * 16 + quad * 4 + i;
      if (r >= M) continue;
      float sc = rsqrtf(fmaxf((float)dego[r], 1.0f));
      unsigned short* cp = C + (size_t)r * cstride + colb + lc;
#pragma unroll
      for (int b = 0; b < 4; b++) cp[b * 16] = f2bf(acc[a][b][i] * sc);
    }
  }
}

// ---------------------------------------------------------------- gathers ---
// 32-lane group per node; cooperative index load + shfl broadcast; 4-deep MLP.
static __device__ __forceinline__ float4 edge_sum32(
    const unsigned short* __restrict__ base, int stride,
    const int* __restrict__ csr, int st, int en, int lane32) {
  float4 s0 = make_float4(0.f, 0.f, 0.f, 0.f);
  float4 s1 = make_float4(0.f, 0.f, 0.f, 0.f);
  float4 s2 = make_float4(0.f, 0.f, 0.f, 0.f);
  float4 s3 = make_float4(0.f, 0.f, 0.f, 0.f);
  for (int b = st; b < en; b += 32) {
    int n = en - b; if (n > 32) n = 32;
    int t = b + lane32;
    int idx = csr[t < en ? t : en - 1];
    int j = 0;
    for (; j + 3 < n; j += 4) {
      int e0 = __shfl(idx, j, 32), e1 = __shfl(idx, j + 1, 32);
      int e2 = __shfl(idx, j + 2, 32), e3 = __shfl(idx, j + 3, 32);
      ushort4 u0 = *(const ushort4*)(base + (size_t)e0 * stride);
      ushort4 u1 = *(const ushort4*)(base + (size_t)e1 * stride);
      ushort4 u2 = *(const ushort4*)(base + (size_t)e2 * stride);
      ushort4 u3 = *(const ushort4*)(base + (size_t)e3 * stride);
      s0.x += bf2f(u0.x); s0.y += bf2f(u0.y); s0.z += bf2f(u0.z); s0.w += bf2f(u0.w);
      s1.x += bf2f(u1.x); s1.y += bf2f(u1.y); s1.z += bf2f(u1.z); s1.w += bf2f(u1.w);
      s2.x += bf2f(u2.x); s2.y += bf2f(u2.y); s2.z += bf2f(u2.z); s2.w += bf2f(u2.w);
      s3.x += bf2f(u3.x); s3.y += bf2f(u3.y); s3.z += bf2f(u3.z); s3.w += bf2f(u3.w);
    }
    for (; j < n; j++) {
      int e0 = __shfl(idx, j, 32);
      ushort4 u0 = *(const ushort4*)(base + (size_t)e0 * stride);
      s0.x += bf2f(u0.x); s0.y += bf2f(u0.y); s0.z += bf2f(u0.z); s0.w += bf2f(u0.w);
    }
  }
  return make_float4(s0.x + s1.x + s2.x + s3.x, s0.y + s1.y + s2.y + s3.y,
                     s0.z + s1.z + s2.z + s3.z, s0.w + s1.w + s2.w + s3.w);
}

// word dst: ww + wwr (h_w3 cols 0-255) + dwr (h_d) -> relu(sum + biases).
// HEAD=0: store bf16 acc row. HEAD=1: fused dot(lin_w)+sigmoid -> out[g].
template <int HEAD>
__global__ __launch_bounds__(256) void gather3_kernel(
    const unsigned short* __restrict__ hw, const unsigned short* __restrict__ hd,
    const int* __restrict__ e1, const int* __restrict__ e2,
    const int* __restrict__ e3,
    const int* __restrict__ c1, const int* __restrict__ c2,
    const int* __restrict__ c3,
    const float* __restrict__ b0, const float* __restrict__ b1,
    const float* __restrict__ b2,
    unsigned short* __restrict__ accb, const float* __restrict__ lw,
    const float* __restrict__ lb, float* __restrict__ out) {
  int g = blockIdx.x * 8 + (threadIdx.x >> 5);
  if (g >= N_W) return;
  int lane32 = threadIdx.x & 31;
  int f = lane32 * 4;

  int st1 = g ? e1[g - 1] : 0, en1 = e1[g];
  int st2 = g ? e2[g - 1] : 0, en2 = e2[g];
  int st3 = g ? e3[g - 1] : 0, en3 = e3[g];
  float4 s1 = edge_sum32(hw + f, 384, c1, st1, en1, lane32);
  float4 s2 = edge_sum32(hw + 128 + f, 384, c2, st2, en2, lane32);
  float4 s3 = edge_sum32(hd + f, 128, c3, st3, en3, lane32);
  float r1 = rsqrtf(fmaxf((float)(en1 - st1), 1.f));
  float r2 = rsqrtf(fmaxf((float)(en2 - st2), 1.f));
  float r3 = rsqrtf(fmaxf((float)(en3 - st3), 1.f));

  float v[4];
#pragma unroll
  for (int i = 0; i < 4; i++) {
    float bb = b0[f + i] + b1[f + i] + b2[f + i];
    v[i] = fmaxf((&s1.x)[i] * r1 + (&s2.x)[i] * r2 + (&s3.x)[i] * r3 + bb, 0.f);
  }
  if (HEAD) {
    float4 w4 = *(const float4*)(lw + f);
    float p = v[0] * w4.x + v[1] * w4.y + v[2] * w4.z + v[3] * w4.w;
#pragma unroll
    for (int off = 16; off > 0; off >>= 1) p += __shfl_down(p, off, 32);
    if (lane32 == 0) out[g] = 1.0f / (1.0f + expf(-(p + lb[0])));
  } else {
    ushort4 o;
    o.x = f2bf(v[0]); o.y = f2bf(v[1]); o.z = f2bf(v[2]); o.w = f2bf(v[3]);
    *(ushort4*)(accb + (size_t)g * 128 + f) = o;
  }
}

// doc dst: wd (h_w3 cols 256-383) -> relu(sum + bias); HEAD as above.
template <int HEAD>
__global__ __launch_bounds__(256) void gather1_kernel(
    const unsigned short* __restrict__ hw, const int* __restrict__ e1,
    const int* __restrict__ c1, const float* __restrict__ b0,
    unsigned short* __restrict__ accb, const float* __restrict__ lw,
    const float* __restrict__ lb, float* __restrict__ out) {
  int g = blockIdx.x * 8 + (threadIdx.x >> 5);
  if (g >= N_D) return;
  int lane32 = threadIdx.x & 31;
  int f = lane32 * 4;
  int st1 = g ? e1[g - 1] : 0, en1 = e1[g];
  float4 s1 = edge_sum32(hw + 256 + f, 384, c1, st1, en1, lane32);
  float r1 = rsqrtf(fmaxf((float)(en1 - st1), 1.f));
  float v[4];
#pragma unroll
  for (int i = 0; i < 4; i++)
    v[i] = fmaxf((&s1.x)[i] * r1 + b0[f + i], 0.f);
  if (HEAD) {
    float4 w4 = *(const float4*)(lw + f);
    float p = v[0] * w4.x + v[1] * w4.y + v[2] * w4.z + v[3] * w4.w;
#pragma unroll
    for (int off = 16; off > 0; off >>= 1) p += __shfl_down(p, off, 32);
    if (lane32 == 0) out[g] = 1.0f / (1.0f + expf(-(p + lb[0])));
  } else {
    ushort4 o;
    o.x = f2bf(v[0]); o.y = f2bf(v[1]); o.z = f2bf(v[2]); o.w = f2bf(v[3]);
    *(ushort4*)(accb + (size_t)g * 128 + f) = o;
  }
}

// ----------------------------------------------------------------- launch ---
extern "C" void kernel_launch(void* const* d_in, const int* in_sizes, int n_in,
                              void* d_out, int out_size, void* d_ws, size_t ws_size,
                              hipStream_t stream) {
  const float* x_word = (const float*)d_in[0];
  const float* x_doc  = (const float*)d_in[1];
  const int* src_ww  = (const int*)d_in[2];
  const int* dst_ww  = (const int*)d_in[3];
  const int* src_wd  = (const int*)d_in[4];
  const int* dst_wd  = (const int*)d_in[5];
  const int* src_wwr = (const int*)d_in[6];
  const int* dst_wwr = (const int*)d_in[7];
  const int* src_dwr = (const int*)d_in[8];
  const int* dst_dwr = (const int*)d_in[9];
  const float* W1_ww  = (const float*)d_in[10]; const float* b1_ww  = (const float*)d_in[11];
  const float* W1_wd  = (const float*)d_in[12]; const float* b1_wd  = (const float*)d_in[13];
  const float* W1_wwr = (const float*)d_in[14]; const float* b1_wwr = (const float*)d_in[15];
  const float* W1_dwr = (const float*)d_in[16]; const float* b1_dwr = (const float*)d_in[17];
  const float* W2_ww  = (const float*)d_in[18]; const float* b2_ww  = (const float*)d_in[19];
  const float* W2_wd  = (const float*)d_in[20]; const float* b2_wd  = (const float*)d_in[21];
  const float* W2_wwr = (const float*)d_in[22]; const float* b2_wwr = (const float*)d_in[23];
  const float* W2_dwr = (const float*)d_in[24]; const float* b2_dwr = (const float*)d_in[25];
  const float* lin_w  = (const float*)d_in[26];
  const float* lin_b  = (const float*)d_in[27];
  float* out = (float*)d_out;

  // ---- workspace layout (4-byte units) ----
  char* ws = (char*)d_ws;
  size_t off = 0;
  auto alloc = [&](size_t n4) { void* p = ws + off * 4; off += n4; return p; };
  int* cur_ww   = (int*)alloc(N_W);
  int* cur_wwr  = (int*)alloc(N_W);
  int* cur_wd   = (int*)alloc(N_D);
  int* cur_dwr  = (int*)alloc(N_W);
  int* dego_ww  = (int*)alloc(N_W);
  int* dego_wwr = (int*)alloc(N_W);
  int* dego_wd  = (int*)alloc(N_W);
  int* dego_dwr = (int*)alloc(N_D);
  const size_t zero4 = off;  // 340000 ints
  int* csr_ww   = (int*)alloc(E_WW);
  int* csr_wwr  = (int*)alloc(E_WW);
  int* csr_wd   = (int*)alloc(E_WD);
  int* csr_dwr  = (int*)alloc(E_WD);
  // xw_bf region (25.6 MB); accW1/accD1 alias it after L1 GEMMs read it
  unsigned short* xw_bf = (unsigned short*)alloc((size_t)N_W * 256 / 2);
  unsigned short* xd_bf = (unsigned short*)alloc((size_t)N_D * 256 / 2);
  unsigned short* h_w3  = (unsigned short*)alloc((size_t)N_W * 384 / 2);
  unsigned short* h_d   = (unsigned short*)alloc((size_t)N_D * 128 / 2);
  unsigned short* Bt1w  = (unsigned short*)alloc(384 * 256 / 2);
  unsigned short* Bt1d  = (unsigned short*)alloc(128 * 256 / 2);
  unsigned short* Bt2w  = (unsigned short*)alloc(384 * 128 / 2);
  unsigned short* Bt2d  = (unsigned short*)alloc(128 * 128 / 2);
  unsigned short* accW1 = xw_bf;                          // [N_W x 128] bf16
  unsigned short* accD1 = xw_bf + (size_t)N_W * 128;      // [N_D x 128] bf16
  (void)ws_size;

  hipMemsetAsync(d_ws, 0, zero4 * 4, stream);

  // ---- bf16 conversions + weight packs ----
  cvt_bf16_kernel<<<(N_W * 256 / 4 + 255) / 256, 256, 0, stream>>>(x_word, xw_bf, N_W * 256 / 4);
  cvt_bf16_kernel<<<(N_D * 256 / 4 + 255) / 256, 256, 0, stream>>>(x_doc, xd_bf, N_D * 256 / 4);
  packB_kernel<<<(384 * 256 + 255) / 256, 256, 0, stream>>>(W1_ww, W1_wwr, W1_wd, 256, 384, Bt1w);
  packB_kernel<<<(128 * 256 + 255) / 256, 256, 0, stream>>>(W1_dwr, W1_dwr, W1_dwr, 256, 128, Bt1d);
  packB_kernel<<<(384 * 128 + 255) / 256, 256, 0, stream>>>(W2_ww, W2_wwr, W2_wd, 128, 384, Bt2w);
  packB_kernel<<<(128 * 128 + 255) / 256, 256, 0, stream>>>(W2_dwr, W2_dwr, W2_dwr, 128, 128, Bt2d);

  // ---- CSR build (once, reused by both layers) ----
  const int gE_ww = (E_WW + 255) / 256, gE_wd = (E_WD + 255) / 256;
  count_kernel<<<gE_ww, 256, 0, stream>>>(src_ww,  dst_ww,  E_WW, dego_ww,  cur_ww);
  count_kernel<<<gE_ww, 256, 0, stream>>>(src_wwr, dst_wwr, E_WW, dego_wwr, cur_wwr);
  count_kernel<<<gE_wd, 256, 0, stream>>>(src_wd,  dst_wd,  E_WD, dego_wd,  cur_wd);
  count_kernel<<<gE_wd, 256, 0, stream>>>(src_dwr, dst_dwr, E_WD, dego_dwr, cur_dwr);
  scan4_kernel<<<4, 1024, 0, stream>>>(cur_ww, N_W, cur_wwr, N_W, cur_wd, N_D, cur_dwr, N_W);
  fill_kernel<<<gE_ww, 256, 0, stream>>>(src_ww,  dst_ww,  E_WW, cur_ww,  csr_ww);
  fill_kernel<<<gE_ww, 256, 0, stream>>>(src_wwr, dst_wwr, E_WW, cur_wwr, csr_wwr);
  fill_kernel<<<gE_wd, 256, 0, stream>>>(src_wd,  dst_wd,  E_WD, cur_wd,  csr_wd);
  fill_kernel<<<gE_wd, 256, 0, stream>>>(src_dwr, dst_dwr, E_WD, cur_dwr, csr_dwr);

  const dim3 gw((N_W + 127) / 128, 3);
  const dim3 gd((N_D + 127) / 128, 1);
  const int ggW = (N_W + 7) / 8, ggD = (N_D + 7) / 8;

  // ---- layer 1 (K=256) ----
  mfma_gemm_kernel<256><<<gw, 256, 0, stream>>>(
      xw_bf, N_W, Bt1w, dego_ww, dego_wwr, dego_wd, h_w3, 384);
  mfma_gemm_kernel<256><<<gd, 256, 0, stream>>>(
      xd_bf, N_D, Bt1d, dego_dwr, dego_dwr, dego_dwr, h_d, 128);
  gather3_kernel<0><<<ggW, 256, 0, stream>>>(
      h_w3, h_d, cur_ww, cur_wwr, cur_dwr, csr_ww, csr_wwr, csr_dwr,
      b1_ww, b1_wwr, b1_dwr, accW1, nullptr, nullptr, nullptr);
  gather1_kernel<0><<<ggD, 256, 0, stream>>>(
      h_w3, cur_wd, csr_wd, b1_wd, accD1, nullptr, nullptr, nullptr);

  // ---- layer 2 (K=128), head fused into gathers ----
  mfma_gemm_kernel<128><<<gw, 256, 0, stream>>>(
      accW1, N_W, Bt2w, dego_ww, dego_wwr, dego_wd, h_w3, 384);
  mfma_gemm_kernel<128><<<gd, 256, 0, stream>>>(
      accD1, N_D, Bt2d, dego_dwr, dego_dwr, dego_dwr, h_d, 128);
  gather3_kernel<1><<<ggW, 256, 0, stream>>>(
      h_w3, h_d, cur_ww, cur_wwr, cur_dwr, csr_ww, csr_wwr, csr_dwr,
      b2_ww, b2_wwr, b2_dwr, nullptr, lin_w, lin_b, out);
  gather1_kernel<1><<<ggD, 256, 0, stream>>>(
      h_w3, cur_wd, csr_wd, b2_wd, nullptr, lin_w, lin_b, out + N_W);
}

// Round 5
// 587.803 us; speedup vs baseline: 10.3405x; 1.1113x over previous
//
#include <hip/hip_runtime.h>
#include <hip/hip_bf16.h>

// GCN_27676769256197 round 5: dispatch fusion (24 -> 7 kernels).
//   - prep: 4x edge-count + 2x bf16-convert + 4x weight-pack, one dispatch
//   - fillgemm1: 4x CSR-fill + layer-1 GEMMs (word 3 col-blocks + doc), one
//     dispatch — fill's atomic/memory waves co-schedule with MFMA waves
//   - gather: word(gather3) + doc(gather1) merged per layer; L2 fuses head
//   - GEMM core unchanged from round 4 (global_load_lds 16B, ds_read_b128,
//     16x16x32 bf16 MFMA, 128x128 tile); gather core unchanged (32-lane
//     group/node, shfl-broadcast indices, 4-deep unroll)

#define N_W 50000
#define N_D 20000
#define E_WW 500000
#define E_WD 300000

typedef __attribute__((ext_vector_type(8))) short short8;
typedef __attribute__((ext_vector_type(4))) float f32x4;

static __device__ __forceinline__ unsigned f2bf_u(float x) {
  unsigned u = __float_as_uint(x);
  return (u + 0x7fff + ((u >> 16) & 1)) >> 16;  // RNE
}
static __device__ __forceinline__ unsigned short f2bf(float x) {
  return (unsigned short)f2bf_u(x);
}
static __device__ __forceinline__ float bf2f(unsigned short b) {
  return __uint_as_float((unsigned)b << 16);
}
static __device__ __forceinline__ void gld16(const void* g, void* l) {
  __builtin_amdgcn_global_load_lds(
      (const __attribute__((address_space(1))) void*)g,
      (__attribute__((address_space(3))) void*)l, 16, 0, 0);
}

struct Args {
  const float *x_word, *x_doc;
  const int *src_ww, *dst_ww, *src_wd, *dst_wd, *src_wwr, *dst_wwr, *src_dwr, *dst_dwr;
  const float *W1_ww, *W1_wd, *W1_wwr, *W1_dwr;
  const float *W2_ww, *W2_wd, *W2_wwr, *W2_dwr;
  const float *b1_ww, *b1_wd, *b1_wwr, *b1_dwr;
  const float *b2_ww, *b2_wd, *b2_wwr, *b2_dwr;
  const float *lin_w, *lin_b;
  float *out;
  int *cur_ww, *cur_wwr, *cur_wd, *cur_dwr;
  int *dego_ww, *dego_wwr, *dego_wd, *dego_dwr;
  int *csr_ww, *csr_wwr, *csr_wd, *csr_dwr;
  unsigned short *xw_bf, *xd_bf, *h_w3, *h_d, *Bt1w, *Bt1d, *Bt2w, *Bt2d;
  unsigned short *accW1, *accD1;
};

// block-range sizes
#define BC_WW 1954   // ceil(E_WW/256)
#define BC_WD 1172   // ceil(E_WD/256)
#define BV_W 12500   // N_W*256/4/256
#define BV_D 5000
#define BP1W 384
#define BP1D 128
#define BP2W 192
#define BP2D 64
#define BG_W 391     // ceil(N_W/128)
#define BG_D 157     // ceil(N_D/128)
#define BGR_W 6250   // N_W/8
#define BGR_D 2500   // N_D/8

// ------------------------------------------------------------ device utils ---
static __device__ __forceinline__ void dev_count(
    const int* __restrict__ src, const int* __restrict__ dst, int E,
    int* __restrict__ dego, int* __restrict__ cur, int i) {
  if (i < E) {
    atomicAdd(&dego[src[i]], 1);
    atomicAdd(&cur[dst[i]], 1);
  }
}
static __device__ __forceinline__ void dev_cvt(
    const float* __restrict__ x, unsigned short* __restrict__ y, int i, int n4) {
  if (i < n4) {
    float4 v = ((const float4*)x)[i];
    ushort4 u;
    u.x = f2bf(v.x); u.y = f2bf(v.y); u.z = f2bf(v.z); u.w = f2bf(v.w);
    ((ushort4*)y)[i] = u;
  }
}
// Bt[n*K + k] = bf16(Wsel[k][n&127]); kshift = log2(K)
static __device__ __forceinline__ void dev_packB(
    const float* __restrict__ W0, const float* __restrict__ W1,
    const float* __restrict__ W2, int kshift, int total, int i,
    unsigned short* __restrict__ out) {
  if (i >= total) return;
  int n = i >> kshift, k = i & ((1 << kshift) - 1);
  const float* W = (n < 128) ? W0 : ((n < 256) ? W1 : W2);
  out[i] = f2bf(W[(size_t)k * 128 + (n & 127)]);
}
static __device__ __forceinline__ void dev_fill(
    const int* __restrict__ src, const int* __restrict__ dst, int E,
    int* __restrict__ cur, int* __restrict__ csr, int i) {
  if (i < E) {
    int pos = atomicAdd(&cur[dst[i]], 1);
    csr[pos] = src[i];
  }
}

// ------------------------------------------------------------------- prep ---
__global__ __launch_bounds__(256) void prep_kernel(Args a) {
  int b = blockIdx.x;
  const int t = threadIdx.x;
  if (b < BC_WW) { dev_count(a.src_ww, a.dst_ww, E_WW, a.dego_ww, a.cur_ww, b * 256 + t); return; }
  b -= BC_WW;
  if (b < BC_WW) { dev_count(a.src_wwr, a.dst_wwr, E_WW, a.dego_wwr, a.cur_wwr, b * 256 + t); return; }
  b -= BC_WW;
  if (b < BC_WD) { dev_count(a.src_wd, a.dst_wd, E_WD, a.dego_wd, a.cur_wd, b * 256 + t); return; }
  b -= BC_WD;
  if (b < BC_WD) { dev_count(a.src_dwr, a.dst_dwr, E_WD, a.dego_dwr, a.cur_dwr, b * 256 + t); return; }
  b -= BC_WD;
  if (b < BV_W) { dev_cvt(a.x_word, a.xw_bf, b * 256 + t, N_W * 64); return; }
  b -= BV_W;
  if (b < BV_D) { dev_cvt(a.x_doc, a.xd_bf, b * 256 + t, N_D * 64); return; }
  b -= BV_D;
  if (b < BP1W) { dev_packB(a.W1_ww, a.W1_wwr, a.W1_wd, 8, 384 * 256, b * 256 + t, a.Bt1w); return; }
  b -= BP1W;
  if (b < BP1D) { dev_packB(a.W1_dwr, a.W1_dwr, a.W1_dwr, 8, 128 * 256, b * 256 + t, a.Bt1d); return; }
  b -= BP1D;
  if (b < BP2W) { dev_packB(a.W2_ww, a.W2_wwr, a.W2_wd, 7, 384 * 128, b * 256 + t, a.Bt2w); return; }
  b -= BP2W;
  dev_packB(a.W2_dwr, a.W2_dwr, a.W2_dwr, 7, 128 * 128, b * 256 + t, a.Bt2d);
}

// ------------------------------------------------------------------- scan ---
__global__ __launch_bounds__(1024) void scan4_kernel(
    int* a0, int n0, int* a1, int n1, int* a2, int n2, int* a3, int n3) {
  int* a; int n;
  switch (blockIdx.x) {
    case 0: a = a0; n = n0; break;
    case 1: a = a1; n = n1; break;
    case 2: a = a2; n = n2; break;
    default: a = a3; n = n3; break;
  }
  __shared__ int wsum[16];
  __shared__ int carry_s;
  const int tid = threadIdx.x;
  const int lane = tid & 63, wave = tid >> 6;
  if (tid == 0) carry_s = 0;
  __syncthreads();
  for (int base = 0; base < n; base += 1024) {
    int idx = base + tid;
    int v = (idx < n) ? a[idx] : 0;
    int s = v;
#pragma unroll
    for (int off = 1; off < 64; off <<= 1) {
      int t = __shfl_up(s, off);
      if (lane >= off) s += t;
    }
    if (lane == 63) wsum[wave] = s;
    __syncthreads();
    int woff = 0;
#pragma unroll
    for (int w = 0; w < 16; w++) woff += (w < wave) ? wsum[w] : 0;
    int excl = carry_s + woff + (s - v);
    if (idx < n) a[idx] = excl;
    __syncthreads();
    if (tid == 0) {
      int tot = 0;
#pragma unroll
      for (int w = 0; w < 16; w++) tot += wsum[w];
      carry_s += tot;
    }
    __syncthreads();
  }
}

// -------------------------------------------------------------- GEMM core ---
// C[r][coloff+c] = bf16(rsqrt(max(dego[r],1)) * sum_k A[r][k]*BtSub[c][k])
template <int K>
static __device__ void dev_gemm(
    const unsigned short* __restrict__ A, int M,
    const unsigned short* __restrict__ BtSub,
    const int* __restrict__ dego,
    unsigned short* __restrict__ C, int cstride, int coloff,
    int bx, unsigned char* smem) {
  const int row0 = bx * 128;
  const int tid = threadIdx.x;
  const int lane = tid & 63;
  const int wave = tid >> 6;
  const int wr = wave >> 1;
  const int wc = wave & 1;
  const int lc = lane & 15;
  const int quad = lane >> 4;

  unsigned char* sA = smem;
  unsigned char* sB = smem + 16384;
  const int mn = tid & 127;
  const int kc0 = tid >> 7;
  const unsigned short* arow = A + (size_t)(row0 + mn) * K;
  const unsigned short* brow = BtSub + (size_t)mn * K;
  unsigned char* ldsA = sA + wave * 1024;
  unsigned char* ldsB = sB + wave * 1024;

  f32x4 acc[4][4];
#pragma unroll
  for (int p = 0; p < 4; p++)
#pragma unroll
    for (int q = 0; q < 4; q++) acc[p][q] = {0.f, 0.f, 0.f, 0.f};

  for (int k0 = 0; k0 < K; k0 += 64) {
#pragma unroll
    for (int i = 0; i < 4; i++) {
      int kk = k0 + (i * 2 + kc0) * 8;
      gld16(arow + kk, ldsA + i * 4096);
      gld16(brow + kk, ldsB + i * 4096);
    }
    __syncthreads();
#pragma unroll
    for (int s = 0; s < 2; s++) {
      const int ko = (s * 4 + quad) * 2048 + lc * 16;
      short8 av[4], bv[4];
#pragma unroll
      for (int p = 0; p < 4; p++)
        av[p] = *(const short8*)(sA + ko + (wr * 64 + p * 16) * 16);
#pragma unroll
      for (int q = 0; q < 4; q++)
        bv[q] = *(const short8*)(sB + ko + (wc * 64 + q * 16) * 16);
#pragma unroll
      for (int p = 0; p < 4; p++)
#pragma unroll
        for (int q = 0; q < 4; q++)
          acc[p][q] = __builtin_amdgcn_mfma_f32_16x16x32_bf16(
              av[p], bv[q], acc[p][q], 0, 0, 0);
    }
    __syncthreads();
  }

  const int colb = coloff + wc * 64;
#pragma unroll
  for (int p = 0; p < 4; p++) {
#pragma unroll
    for (int i = 0; i < 4; i++) {
      int r = row0 + wr * 64 + p * 16 + quad * 4 + i;
      if (r >= M) continue;
      float sc = rsqrtf(fmaxf((float)dego[r], 1.0f));
      unsigned short* cp = C + (size_t)r * cstride + colb + lc;
#pragma unroll
      for (int q = 0; q < 4; q++) cp[q * 16] = f2bf(acc[p][q][i] * sc);
    }
  }
}

// --------------------------------------------- fill + layer-1 GEMM (fused) ---
__global__ __launch_bounds__(256) void fillgemm1_kernel(Args a) {
  __shared__ __align__(16) unsigned char smem[32768];
  int b = blockIdx.x;
  const int t = threadIdx.x;
  if (b < BC_WW) { dev_fill(a.src_ww, a.dst_ww, E_WW, a.cur_ww, a.csr_ww, b * 256 + t); return; }
  b -= BC_WW;
  if (b < BC_WW) { dev_fill(a.src_wwr, a.dst_wwr, E_WW, a.cur_wwr, a.csr_wwr, b * 256 + t); return; }
  b -= BC_WW;
  if (b < BC_WD) { dev_fill(a.src_wd, a.dst_wd, E_WD, a.cur_wd, a.csr_wd, b * 256 + t); return; }
  b -= BC_WD;
  if (b < BC_WD) { dev_fill(a.src_dwr, a.dst_dwr, E_WD, a.cur_dwr, a.csr_dwr, b * 256 + t); return; }
  b -= BC_WD;
  if (b < BG_W) { dev_gemm<256>(a.xw_bf, N_W, a.Bt1w,                     a.dego_ww,  a.h_w3, 384, 0,   b, smem); return; }
  b -= BG_W;
  if (b < BG_W) { dev_gemm<256>(a.xw_bf, N_W, a.Bt1w + (size_t)128 * 256, a.dego_wwr, a.h_w3, 384, 128, b, smem); return; }
  b -= BG_W;
  if (b < BG_W) { dev_gemm<256>(a.xw_bf, N_W, a.Bt1w + (size_t)256 * 256, a.dego_wd,  a.h_w3, 384, 256, b, smem); return; }
  b -= BG_W;
  dev_gemm<256>(a.xd_bf, N_D, a.Bt1d, a.dego_dwr, a.h_d, 128, 0, b, smem);
}

// ------------------------------------------------------------ layer-2 GEMM ---
__global__ __launch_bounds__(256) void gemm2_kernel(Args a) {
  __shared__ __align__(16) unsigned char smem[32768];
  int b = blockIdx.x;
  if (b < BG_W) { dev_gemm<128>(a.accW1, N_W, a.Bt2w,                     a.dego_ww,  a.h_w3, 384, 0,   b, smem); return; }
  b -= BG_W;
  if (b < BG_W) { dev_gemm<128>(a.accW1, N_W, a.Bt2w + (size_t)128 * 128, a.dego_wwr, a.h_w3, 384, 128, b, smem); return; }
  b -= BG_W;
  if (b < BG_W) { dev_gemm<128>(a.accW1, N_W, a.Bt2w + (size_t)256 * 128, a.dego_wd,  a.h_w3, 384, 256, b, smem); return; }
  b -= BG_W;
  dev_gemm<128>(a.accD1, N_D, a.Bt2d, a.dego_dwr, a.h_d, 128, 0, b, smem);
}

// ---------------------------------------------------------------- gathers ---
static __device__ __forceinline__ float4 edge_sum32(
    const unsigned short* __restrict__ base, int stride,
    const int* __restrict__ csr, int st, int en, int lane32) {
  float4 s0 = make_float4(0.f, 0.f, 0.f, 0.f);
  float4 s1 = make_float4(0.f, 0.f, 0.f, 0.f);
  float4 s2 = make_float4(0.f, 0.f, 0.f, 0.f);
  float4 s3 = make_float4(0.f, 0.f, 0.f, 0.f);
  for (int b = st; b < en; b += 32) {
    int n = en - b; if (n > 32) n = 32;
    int t = b + lane32;
    int idx = csr[t < en ? t : en - 1];
    int j = 0;
    for (; j + 3 < n; j += 4) {
      int e0 = __shfl(idx, j, 32), e1 = __shfl(idx, j + 1, 32);
      int e2 = __shfl(idx, j + 2, 32), e3 = __shfl(idx, j + 3, 32);
      ushort4 u0 = *(const ushort4*)(base + (size_t)e0 * stride);
      ushort4 u1 = *(const ushort4*)(base + (size_t)e1 * stride);
      ushort4 u2 = *(const ushort4*)(base + (size_t)e2 * stride);
      ushort4 u3 = *(const ushort4*)(base + (size_t)e3 * stride);
      s0.x += bf2f(u0.x); s0.y += bf2f(u0.y); s0.z += bf2f(u0.z); s0.w += bf2f(u0.w);
      s1.x += bf2f(u1.x); s1.y += bf2f(u1.y); s1.z += bf2f(u1.z); s1.w += bf2f(u1.w);
      s2.x += bf2f(u2.x); s2.y += bf2f(u2.y); s2.z += bf2f(u2.z); s2.w += bf2f(u2.w);
      s3.x += bf2f(u3.x); s3.y += bf2f(u3.y); s3.z += bf2f(u3.z); s3.w += bf2f(u3.w);
    }
    for (; j < n; j++) {
      int e0 = __shfl(idx, j, 32);
      ushort4 u0 = *(const ushort4*)(base + (size_t)e0 * stride);
      s0.x += bf2f(u0.x); s0.y += bf2f(u0.y); s0.z += bf2f(u0.z); s0.w += bf2f(u0.w);
    }
  }
  return make_float4(s0.x + s1.x + s2.x + s3.x, s0.y + s1.y + s2.y + s3.y,
                     s0.z + s1.z + s2.z + s3.z, s0.w + s1.w + s2.w + s3.w);
}

// merged word+doc gather. HEAD=0: layer-1 biases, bf16 acc store.
// HEAD=1: layer-2 biases, fused dot(lin_w)+sigmoid -> out.
template <int HEAD>
__global__ __launch_bounds__(256) void gather_kernel(Args a) {
  const int lane32 = threadIdx.x & 31;
  const int f = lane32 * 4;
  int blk = blockIdx.x;
  float v[4];
  float* outp;
  unsigned short* accp;

  if (blk < BGR_W) {
    int g = blk * 8 + (threadIdx.x >> 5);
    int st1 = g ? a.cur_ww[g - 1] : 0,  en1 = a.cur_ww[g];
    int st2 = g ? a.cur_wwr[g - 1] : 0, en2 = a.cur_wwr[g];
    int st3 = g ? a.cur_dwr[g - 1] : 0, en3 = a.cur_dwr[g];
    float4 s1 = edge_sum32(a.h_w3 + f, 384, a.csr_ww, st1, en1, lane32);
    float4 s2 = edge_sum32(a.h_w3 + 128 + f, 384, a.csr_wwr, st2, en2, lane32);
    float4 s3 = edge_sum32(a.h_d + f, 128, a.csr_dwr, st3, en3, lane32);
    float r1 = rsqrtf(fmaxf((float)(en1 - st1), 1.f));
    float r2 = rsqrtf(fmaxf((float)(en2 - st2), 1.f));
    float r3 = rsqrtf(fmaxf((float)(en3 - st3), 1.f));
    const float* b0 = HEAD ? a.b2_ww : a.b1_ww;
    const float* b1 = HEAD ? a.b2_wwr : a.b1_wwr;
    const float* b2 = HEAD ? a.b2_dwr : a.b1_dwr;
#pragma unroll
    for (int i = 0; i < 4; i++) {
      float bb = b0[f + i] + b1[f + i] + b2[f + i];
      v[i] = fmaxf((&s1.x)[i] * r1 + (&s2.x)[i] * r2 + (&s3.x)[i] * r3 + bb, 0.f);
    }
    outp = a.out + g;
    accp = a.accW1 + (size_t)g * 128 + f;
  } else {
    int g = (blk - BGR_W) * 8 + (threadIdx.x >> 5);
    int st1 = g ? a.cur_wd[g - 1] : 0, en1 = a.cur_wd[g];
    float4 s1 = edge_sum32(a.h_w3 + 256 + f, 384, a.csr_wd, st1, en1, lane32);
    float r1 = rsqrtf(fmaxf((float)(en1 - st1), 1.f));
    const float* b0 = HEAD ? a.b2_wd : a.b1_wd;
#pragma unroll
    for (int i = 0; i < 4; i++)
      v[i] = fmaxf((&s1.x)[i] * r1 + b0[f + i], 0.f);
    outp = a.out + N_W + g;
    accp = a.accD1 + (size_t)g * 128 + f;
  }

  if (HEAD) {
    float4 w4 = *(const float4*)(a.lin_w + f);
    float p = v[0] * w4.x + v[1] * w4.y + v[2] * w4.z + v[3] * w4.w;
#pragma unroll
    for (int off = 16; off > 0; off >>= 1) p += __shfl_down(p, off, 32);
    if (lane32 == 0) *outp = 1.0f / (1.0f + expf(-(p + a.lin_b[0])));
  } else {
    ushort4 o;
    o.x = f2bf(v[0]); o.y = f2bf(v[1]); o.z = f2bf(v[2]); o.w = f2bf(v[3]);
    *(ushort4*)accp = o;
  }
}

// ----------------------------------------------------------------- launch ---
extern "C" void kernel_launch(void* const* d_in, const int* in_sizes, int n_in,
                              void* d_out, int out_size, void* d_ws, size_t ws_size,
                              hipStream_t stream) {
  Args a;
  a.x_word = (const float*)d_in[0];
  a.x_doc  = (const float*)d_in[1];
  a.src_ww  = (const int*)d_in[2];
  a.dst_ww  = (const int*)d_in[3];
  a.src_wd  = (const int*)d_in[4];
  a.dst_wd  = (const int*)d_in[5];
  a.src_wwr = (const int*)d_in[6];
  a.dst_wwr = (const int*)d_in[7];
  a.src_dwr = (const int*)d_in[8];
  a.dst_dwr = (const int*)d_in[9];
  a.W1_ww  = (const float*)d_in[10]; a.b1_ww  = (const float*)d_in[11];
  a.W1_wd  = (const float*)d_in[12]; a.b1_wd  = (const float*)d_in[13];
  a.W1_wwr = (const float*)d_in[14]; a.b1_wwr = (const float*)d_in[15];
  a.W1_dwr = (const float*)d_in[16]; a.b1_dwr = (const float*)d_in[17];
  a.W2_ww  = (const float*)d_in[18]; a.b2_ww  = (const float*)d_in[19];
  a.W2_wd  = (const float*)d_in[20]; a.b2_wd  = (const float*)d_in[21];
  a.W2_wwr = (const float*)d_in[22]; a.b2_wwr = (const float*)d_in[23];
  a.W2_dwr = (const float*)d_in[24]; a.b2_dwr = (const float*)d_in[25];
  a.lin_w  = (const float*)d_in[26];
  a.lin_b  = (const float*)d_in[27];
  a.out = (float*)d_out;

  // ---- workspace layout (4-byte units) ----
  char* ws = (char*)d_ws;
  size_t off = 0;
  auto alloc = [&](size_t n4) { void* p = ws + off * 4; off += n4; return p; };
  a.cur_ww   = (int*)alloc(N_W);
  a.cur_wwr  = (int*)alloc(N_W);
  a.cur_wd   = (int*)alloc(N_D);
  a.cur_dwr  = (int*)alloc(N_W);
  a.dego_ww  = (int*)alloc(N_W);
  a.dego_wwr = (int*)alloc(N_W);
  a.dego_wd  = (int*)alloc(N_W);
  a.dego_dwr = (int*)alloc(N_D);
  const size_t zero4 = off;  // 340000 ints
  a.csr_ww   = (int*)alloc(E_WW);
  a.csr_wwr  = (int*)alloc(E_WW);
  a.csr_wd   = (int*)alloc(E_WD);
  a.csr_dwr  = (int*)alloc(E_WD);
  a.xw_bf = (unsigned short*)alloc((size_t)N_W * 256 / 2);
  a.xd_bf = (unsigned short*)alloc((size_t)N_D * 256 / 2);
  a.h_w3  = (unsigned short*)alloc((size_t)N_W * 384 / 2);
  a.h_d   = (unsigned short*)alloc((size_t)N_D * 128 / 2);
  a.Bt1w  = (unsigned short*)alloc(384 * 256 / 2);
  a.Bt1d  = (unsigned short*)alloc(128 * 256 / 2);
  a.Bt2w  = (unsigned short*)alloc(384 * 128 / 2);
  a.Bt2d  = (unsigned short*)alloc(128 * 128 / 2);
  a.accW1 = a.xw_bf;                          // alias: dead after L1 GEMMs
  a.accD1 = a.xw_bf + (size_t)N_W * 128;
  (void)ws_size;

  hipMemsetAsync(d_ws, 0, zero4 * 4, stream);

  prep_kernel<<<2 * BC_WW + 2 * BC_WD + BV_W + BV_D + BP1W + BP1D + BP2W + BP2D,
                256, 0, stream>>>(a);
  scan4_kernel<<<4, 1024, 0, stream>>>(a.cur_ww, N_W, a.cur_wwr, N_W,
                                       a.cur_wd, N_D, a.cur_dwr, N_W);
  fillgemm1_kernel<<<2 * BC_WW + 2 * BC_WD + 3 * BG_W + BG_D, 256, 0, stream>>>(a);
  gather_kernel<0><<<BGR_W + BGR_D, 256, 0, stream>>>(a);
  gemm2_kernel<<<3 * BG_W + BG_D, 256, 0, stream>>>(a);
  gather_kernel<1><<<BGR_W + BGR_D, 256, 0, stream>>>(a);
}